// Round 9
// baseline (76.744 us; speedup 1.0000x reference)
//
#include <hip/hip_runtime.h>
#include <math.h>

#define MM 32
#define NN 8192
#define DD 64
#define KK 16

typedef float f32x4 __attribute__((ext_vector_type(4)));

// ---------------------------------------------------------------------------
// Kernel 1: lite per-component precompute via Woodbury. 32 blocks x 64 thr.
//   Mk = I + Lambda^T P^{-1} Lambda (16x16); Minv[m] = Mk^{-1};
//   cconst[m] = log(pi+1e-10) - 0.5*(D log2pi + logdetP + logdetM)
// ---------------------------------------------------------------------------
__global__ __launch_bounds__(64) void mfa_pre(
    const float* __restrict__ pi, const float* __restrict__ Lambda,
    const float* __restrict__ Psi, float* __restrict__ Minv_out,
    float* __restrict__ const_out) {
  const int m = blockIdx.x;
  const int t = threadIdx.x;
  __shared__ float lam[DD * KK];   // 4KB
  __shared__ float pinv[DD];
  __shared__ float Mmat[KK * KK];
  __shared__ float Lmat[KK * KK];
  __shared__ float vbuf[KK];
  __shared__ float red[DD];

  const float4* Lg = reinterpret_cast<const float4*>(Lambda + (size_t)m * DD * KK);
  float4* lam4 = reinterpret_cast<float4*>(lam);
  for (int i = t; i < DD * KK / 4; i += 64) lam4[i] = Lg[i];
  if (t < DD) pinv[t] = 1.0f / (Psi[t] + 1e-6f);
  __syncthreads();

  // Mk: thread t -> column j = t&15, rows k = (t>>4) + 4r (4 entries).
  {
    const int j = t & 15;
    const int k0 = t >> 4;
    float acc[4] = {0.f, 0.f, 0.f, 0.f};
    for (int d = 0; d < DD; ++d) {
      const float cj = lam[d * KK + j] * pinv[d];
#pragma unroll
      for (int r = 0; r < 4; ++r) acc[r] += lam[d * KK + (k0 + 4 * r)] * cj;
    }
#pragma unroll
    for (int r = 0; r < 4; ++r) {
      const int k = k0 + 4 * r;
      Mmat[k * KK + j] = acc[r] + (k == j ? 1.0f : 0.0f);
    }
  }
  __syncthreads();

  // Cooperative right-looking Cholesky: thread r owns row r in registers.
  float lr[KK];
  if (t < KK) {
#pragma unroll
    for (int j = 0; j < KK; ++j) lr[j] = Mmat[t * KK + j];
  }
#pragma unroll
  for (int c = 0; c < KK; ++c) {
    if (t < KK) vbuf[t] = lr[c];
    __syncthreads();
    if (t < KK) {
      const float vc = vbuf[c];
      const float dc = sqrtf(vc);
      if (t >= c) Lmat[t * KK + c] = lr[c] / dc;
      const float s = lr[c] / vc;
#pragma unroll
      for (int j = 0; j < KK; ++j)
        if (j > c) lr[j] -= s * vbuf[j];
    }
    __syncthreads();
  }

  // parallel logs
  if (t < DD) red[t] = logf(pinv[t]);
  if (t < KK) vbuf[t] = logf(Lmat[t * KK + t]);

  // Minv via two triangular solves per unit column (thread = column).
  if (t < KK) {
    const int col = t;
    float y[KK], z[KK];
#pragma unroll
    for (int i = 0; i < KK; ++i) {
      float s = (i == col) ? 1.0f : 0.0f;
#pragma unroll
      for (int p = 0; p < KK; ++p)
        if (p < i) s -= Lmat[i * KK + p] * y[p];
      y[i] = s / Lmat[i * KK + i];
    }
#pragma unroll
    for (int i = KK - 1; i >= 0; --i) {
      float s = y[i];
#pragma unroll
      for (int p = 0; p < KK; ++p)
        if (p > i) s -= Lmat[p * KK + i] * z[p];
      z[i] = s / Lmat[i * KK + i];
    }
#pragma unroll
    for (int i = 0; i < KK; ++i)
      Minv_out[(size_t)m * KK * KK + i * KK + col] = z[i];
  }
  __syncthreads();

  if (t == 0) {
    float sl = 0.0f;  // sum log pinv  (logdetP = -sl)
    for (int d = 0; d < DD; ++d) sl += red[d];
    float lM = 0.0f;
#pragma unroll
    for (int c = 0; c < KK; ++c) lM += vbuf[c];
    const float LOG2PI = 1.8378770664093453f;
    const_out[m] =
        logf(pi[m] + 1e-10f) - 0.5f * (DD * LOG2PI - sl + 2.0f * lM);
  }
}

// ---------------------------------------------------------------------------
// Kernel 2: fused main pass (R8 structure). NEW: write-locality swizzle —
// 1D grid of 1024; block b -> q=b>>8, r=b&255, m=r>>3, ntile=(r&7)*4+q.
// Blocks co-resident on a CU (ids congruent mod 256) share r -> same m and
// 4 CONSECUTIVE n-tiles, so each CU's 16 wave store-streams fall in one
// contiguous ~1MB e_zz window (DRAM row locality) instead of 4 regions
// 64MB apart. __launch_bounds__(256,4) guarantees 16 waves/CU (VGPR<=128).
// ---------------------------------------------------------------------------
__global__ __launch_bounds__(256, 4) void mfa_main(
    const float* __restrict__ X, const float* __restrict__ mu,
    const float* __restrict__ Lambda, const float* __restrict__ Psi,
    const float* __restrict__ Minv, const float* __restrict__ cconst,
    float* __restrict__ scr, float* __restrict__ out) {
  const int b = blockIdx.x;
  const int q = b >> 8;                        // 0..3
  const int r = b & 255;
  const int m = r >> 3;                        // 0..31
  const int n0 = (((r & 7) << 2) + q) << 8;    // ntile*256
  const int tid = threadIdx.x;
  const int w = tid >> 6, l = tid & 63;

  __shared__ float ez_l[256 * KK];  // 16KB, wave w owns [w*64*KK, +4KB)

  const float* lamG = Lambda + (size_t)m * DD * KK;  // uniform rows
  const float* mum = mu + m * DD;
  const float* Mi = Minv + (size_t)m * KK * KK;
  const float cst = cconst[m];

  const int n = n0 + tid;

  float u[KK];
#pragma unroll
  for (int k = 0; k < KK; ++k) u[k] = 0.0f;
  float q_ = 0.0f;
  const float4* X4 = reinterpret_cast<const float4*>(X + (size_t)n * DD);
#pragma unroll
  for (int d4 = 0; d4 < DD / 4; ++d4) {
    const float4 xv = X4[d4];                                           // lane
    const float4 muv = *reinterpret_cast<const float4*>(mum + d4 * 4);  // unif
    const float4 psv = *reinterpret_cast<const float4*>(Psi + d4 * 4);  // unif
    const float xs[4] = {xv.x, xv.y, xv.z, xv.w};
    const float ms[4] = {muv.x, muv.y, muv.z, muv.w};
    const float ps[4] = {psv.x, psv.y, psv.z, psv.w};
#pragma unroll
    for (int s = 0; s < 4; ++s) {
      const int d = d4 * 4 + s;
      const float df = xs[s] - ms[s];
      const float dfp = df * __builtin_amdgcn_rcpf(ps[s] + 1e-6f);
      q_ += df * dfp;
      const float4* wr = reinterpret_cast<const float4*>(lamG + d * KK);
#pragma unroll
      for (int k4 = 0; k4 < 4; ++k4) {
        const float4 wv = wr[k4];  // uniform
        u[k4 * 4 + 0] += wv.x * dfp;
        u[k4 * 4 + 1] += wv.y * dfp;
        u[k4 * 4 + 2] += wv.z * dfp;
        u[k4 * 4 + 3] += wv.w * dfp;
      }
    }
  }

  // e_z = Minv u (f32x4 quads -> ds_write_b128), udot alongside
  float udot = 0.0f;
  float* ezrow = ez_l + (size_t)tid * KK;
#pragma unroll
  for (int i4 = 0; i4 < 4; ++i4) {
    f32x4 ezv;
#pragma unroll
    for (int ii = 0; ii < 4; ++ii) {
      const int i = i4 * 4 + ii;
      const float4* mr = reinterpret_cast<const float4*>(Mi + i * KK);
      float s = 0.0f;
#pragma unroll
      for (int j4 = 0; j4 < 4; ++j4) {
        const float4 mv = mr[j4];  // uniform
        s += mv.x * u[j4 * 4 + 0] + mv.y * u[j4 * 4 + 1] +
             mv.z * u[j4 * 4 + 2] + mv.w * u[j4 * 4 + 3];
      }
      ezv[ii] = s;
      udot += u[i] * s;
    }
    *reinterpret_cast<f32x4*>(ezrow + i4 * 4) = ezv;
  }
  scr[(size_t)m * NN + n] = cst - 0.5f * (q_ - udot);  // contiguous logit

  // ---- wave-local phase switch (no __syncthreads) ----
  __builtin_amdgcn_wave_barrier();
  asm volatile("s_waitcnt lgkmcnt(0)" ::: "memory");

  const int sbase = n0 + w * 64;  // first sample owned by this wave
  const f32x4* ezl4 =
      reinterpret_cast<const f32x4*>(ez_l + (size_t)w * 64 * KK);

  // e_z out: wave's 64 samples * 16 floats = 256 float4, coalesced
  f32x4* ezo = reinterpret_cast<f32x4*>(
      out + (size_t)NN * MM + ((size_t)m * NN + sbase) * KK);
#pragma unroll
  for (int it = 0; it < 4; ++it) ezo[it * 64 + l] = ezl4[it * 64 + l];

  // e_zz out: per iteration the wave writes one sample's full 16x16 tile
  // (64 lanes x float4 = 1KB, coalesced). lane l: row l>>2, col-quad l&3.
  const int i_ = l >> 2, jq = l & 3;
  const f32x4 mreg = reinterpret_cast<const f32x4*>(Mi)[l];  // per-lane
  f32x4* zzo = reinterpret_cast<f32x4*>(out + (size_t)NN * MM +
                                        (size_t)MM * NN * KK) +
               ((size_t)m * NN + sbase) * 64;
#pragma unroll 4
  for (int nl = 0; nl < 64; ++nl) {
    const float ezi = ez_l[((size_t)w * 64 + nl) * KK + i_];
    const f32x4 ezj = ezl4[nl * 4 + jq];
    zzo[nl * 64 + l] = mreg + ezi * ezj;
  }
}

// ---------------------------------------------------------------------------
// Kernel 3: softmax. 128 blocks x 64 threads. Reads scratch [M,N]
// (coalesced), writes resp [N,M] coalesced.
// ---------------------------------------------------------------------------
__global__ __launch_bounds__(64) void mfa_softmax(
    const float* __restrict__ scr, float* __restrict__ out) {
  const int n = blockIdx.x * 64 + threadIdx.x;
  float v[MM];
#pragma unroll
  for (int m = 0; m < MM; ++m) v[m] = scr[(size_t)m * NN + n];
  float mx = -3.4e38f;
#pragma unroll
  for (int i = 0; i < MM; ++i) mx = fmaxf(mx, v[i]);
  float s = 0.0f;
#pragma unroll
  for (int i = 0; i < MM; ++i) { v[i] = expf(v[i] - mx); s += v[i]; }
  const float inv = 1.0f / s;
  float4* p = reinterpret_cast<float4*>(out) + (size_t)n * (MM / 4);
#pragma unroll
  for (int i = 0; i < MM / 4; ++i) {
    float4 t;
    t.x = v[4 * i] * inv; t.y = v[4 * i + 1] * inv;
    t.z = v[4 * i + 2] * inv; t.w = v[4 * i + 3] * inv;
    p[i] = t;
  }
}

extern "C" void kernel_launch(void* const* d_in, const int* in_sizes, int n_in,
                              void* d_out, int out_size, void* d_ws,
                              size_t ws_size, hipStream_t stream) {
  const float* X = (const float*)d_in[0];
  const float* pi = (const float*)d_in[1];
  const float* mu = (const float*)d_in[2];
  const float* Lambda = (const float*)d_in[3];
  const float* Psi = (const float*)d_in[4];
  float* out = (float*)d_out;

  float* Minv = (float*)d_ws;            // 32*256 floats
  float* cconst = Minv + MM * KK * KK;   // 32
  float* scr = cconst + MM;              // 32*8192 floats = 1MB

  mfa_pre<<<MM, 64, 0, stream>>>(pi, Lambda, Psi, Minv, cconst);
  mfa_main<<<1024, 256, 0, stream>>>(X, mu, Lambda, Psi, Minv, cconst, scr,
                                     out);
  mfa_softmax<<<NN / 64, 64, 0, stream>>>(scr, out);
}

// Round 10
// 73.907 us; speedup vs baseline: 1.0384x; 1.0384x over previous
//
#include <hip/hip_runtime.h>
#include <math.h>

#define MM 32
#define NN 8192
#define DD 64
#define KK 16

typedef float f32x4 __attribute__((ext_vector_type(4)));

// ---------------------------------------------------------------------------
// Kernel 1: lite per-component precompute via Woodbury. 32 blocks x 64 thr.
//   Mk = I + Lambda^T P^{-1} Lambda (16x16); Minv[m] = Mk^{-1};
//   cconst[m] = log(pi+1e-10) - 0.5*(D log2pi + logdetP + logdetM)
// ---------------------------------------------------------------------------
__global__ __launch_bounds__(64) void mfa_pre(
    const float* __restrict__ pi, const float* __restrict__ Lambda,
    const float* __restrict__ Psi, float* __restrict__ Minv_out,
    float* __restrict__ const_out) {
  const int m = blockIdx.x;
  const int t = threadIdx.x;
  __shared__ float lam[DD * KK];   // 4KB
  __shared__ float pinv[DD];
  __shared__ float Mmat[KK * KK];
  __shared__ float Lmat[KK * KK];
  __shared__ float vbuf[KK];
  __shared__ float red[DD];

  const float4* Lg = reinterpret_cast<const float4*>(Lambda + (size_t)m * DD * KK);
  float4* lam4 = reinterpret_cast<float4*>(lam);
  for (int i = t; i < DD * KK / 4; i += 64) lam4[i] = Lg[i];
  if (t < DD) pinv[t] = 1.0f / (Psi[t] + 1e-6f);
  __syncthreads();

  // Mk: thread t -> column j = t&15, rows k = (t>>4) + 4r (4 entries).
  {
    const int j = t & 15;
    const int k0 = t >> 4;
    float acc[4] = {0.f, 0.f, 0.f, 0.f};
    for (int d = 0; d < DD; ++d) {
      const float cj = lam[d * KK + j] * pinv[d];
#pragma unroll
      for (int r = 0; r < 4; ++r) acc[r] += lam[d * KK + (k0 + 4 * r)] * cj;
    }
#pragma unroll
    for (int r = 0; r < 4; ++r) {
      const int k = k0 + 4 * r;
      Mmat[k * KK + j] = acc[r] + (k == j ? 1.0f : 0.0f);
    }
  }
  __syncthreads();

  // Cooperative right-looking Cholesky: thread r owns row r in registers.
  float lr[KK];
  if (t < KK) {
#pragma unroll
    for (int j = 0; j < KK; ++j) lr[j] = Mmat[t * KK + j];
  }
#pragma unroll
  for (int c = 0; c < KK; ++c) {
    if (t < KK) vbuf[t] = lr[c];
    __syncthreads();
    if (t < KK) {
      const float vc = vbuf[c];
      const float dc = sqrtf(vc);
      if (t >= c) Lmat[t * KK + c] = lr[c] / dc;
      const float s = lr[c] / vc;
#pragma unroll
      for (int j = 0; j < KK; ++j)
        if (j > c) lr[j] -= s * vbuf[j];
    }
    __syncthreads();
  }

  // parallel logs
  if (t < DD) red[t] = logf(pinv[t]);
  if (t < KK) vbuf[t] = logf(Lmat[t * KK + t]);

  // Minv via two triangular solves per unit column (thread = column).
  if (t < KK) {
    const int col = t;
    float y[KK], z[KK];
#pragma unroll
    for (int i = 0; i < KK; ++i) {
      float s = (i == col) ? 1.0f : 0.0f;
#pragma unroll
      for (int p = 0; p < KK; ++p)
        if (p < i) s -= Lmat[i * KK + p] * y[p];
      y[i] = s / Lmat[i * KK + i];
    }
#pragma unroll
    for (int i = KK - 1; i >= 0; --i) {
      float s = y[i];
#pragma unroll
      for (int p = 0; p < KK; ++p)
        if (p > i) s -= Lmat[p * KK + i] * z[p];
      z[i] = s / Lmat[i * KK + i];
    }
#pragma unroll
    for (int i = 0; i < KK; ++i)
      Minv_out[(size_t)m * KK * KK + i * KK + col] = z[i];
  }
  __syncthreads();

  if (t == 0) {
    float sl = 0.0f;  // sum log pinv  (logdetP = -sl)
    for (int d = 0; d < DD; ++d) sl += red[d];
    float lM = 0.0f;
#pragma unroll
    for (int c = 0; c < KK; ++c) lM += vbuf[c];
    const float LOG2PI = 1.8378770664093453f;
    const_out[m] =
        logf(pi[m] + 1e-10f) - 0.5f * (DD * LOG2PI - sl + 2.0f * lM);
  }
}

// ---------------------------------------------------------------------------
// Kernel 2: fused main pass (measured-best R8 configuration, verbatim).
// grid = (N/256, M) 2D; barrier-free wave-local pipeline; params via uniform
// global loads; logits to contiguous scratch [M,N]; ez staged via
// ds_write_b128; cached coalesced 1KB-tile stores for e_z / e_zz.
// ---------------------------------------------------------------------------
__global__ __launch_bounds__(256) void mfa_main(
    const float* __restrict__ X, const float* __restrict__ mu,
    const float* __restrict__ Lambda, const float* __restrict__ Psi,
    const float* __restrict__ Minv, const float* __restrict__ cconst,
    float* __restrict__ scr, float* __restrict__ out) {
  const int m = blockIdx.y;
  const int n0 = blockIdx.x * 256;
  const int tid = threadIdx.x;
  const int w = tid >> 6, l = tid & 63;

  __shared__ float ez_l[256 * KK];  // 16KB, wave w owns [w*64*KK, +4KB)

  const float* lamG = Lambda + (size_t)m * DD * KK;  // uniform rows
  const float* mum = mu + m * DD;
  const float* Mi = Minv + (size_t)m * KK * KK;
  const float cst = cconst[m];

  const int n = n0 + tid;

  float u[KK];
#pragma unroll
  for (int k = 0; k < KK; ++k) u[k] = 0.0f;
  float q = 0.0f;
  const float4* X4 = reinterpret_cast<const float4*>(X + (size_t)n * DD);
#pragma unroll
  for (int d4 = 0; d4 < DD / 4; ++d4) {
    const float4 xv = X4[d4];                                           // lane
    const float4 muv = *reinterpret_cast<const float4*>(mum + d4 * 4);  // unif
    const float4 psv = *reinterpret_cast<const float4*>(Psi + d4 * 4);  // unif
    const float xs[4] = {xv.x, xv.y, xv.z, xv.w};
    const float ms[4] = {muv.x, muv.y, muv.z, muv.w};
    const float ps[4] = {psv.x, psv.y, psv.z, psv.w};
#pragma unroll
    for (int s = 0; s < 4; ++s) {
      const int d = d4 * 4 + s;
      const float df = xs[s] - ms[s];
      const float dfp = df * __builtin_amdgcn_rcpf(ps[s] + 1e-6f);
      q += df * dfp;
      const float4* wr = reinterpret_cast<const float4*>(lamG + d * KK);
#pragma unroll
      for (int k4 = 0; k4 < 4; ++k4) {
        const float4 wv = wr[k4];  // uniform
        u[k4 * 4 + 0] += wv.x * dfp;
        u[k4 * 4 + 1] += wv.y * dfp;
        u[k4 * 4 + 2] += wv.z * dfp;
        u[k4 * 4 + 3] += wv.w * dfp;
      }
    }
  }

  // e_z = Minv u (f32x4 quads -> ds_write_b128), udot alongside
  float udot = 0.0f;
  float* ezrow = ez_l + (size_t)tid * KK;
#pragma unroll
  for (int i4 = 0; i4 < 4; ++i4) {
    f32x4 ezv;
#pragma unroll
    for (int ii = 0; ii < 4; ++ii) {
      const int i = i4 * 4 + ii;
      const float4* mr = reinterpret_cast<const float4*>(Mi + i * KK);
      float s = 0.0f;
#pragma unroll
      for (int j4 = 0; j4 < 4; ++j4) {
        const float4 mv = mr[j4];  // uniform
        s += mv.x * u[j4 * 4 + 0] + mv.y * u[j4 * 4 + 1] +
             mv.z * u[j4 * 4 + 2] + mv.w * u[j4 * 4 + 3];
      }
      ezv[ii] = s;
      udot += u[i] * s;
    }
    *reinterpret_cast<f32x4*>(ezrow + i4 * 4) = ezv;
  }
  scr[(size_t)m * NN + n] = cst - 0.5f * (q - udot);  // contiguous logit

  // ---- wave-local phase switch (no __syncthreads) ----
  __builtin_amdgcn_wave_barrier();
  asm volatile("s_waitcnt lgkmcnt(0)" ::: "memory");

  const int sbase = n0 + w * 64;  // first sample owned by this wave
  const f32x4* ezl4 =
      reinterpret_cast<const f32x4*>(ez_l + (size_t)w * 64 * KK);

  // e_z out: wave's 64 samples * 16 floats = 256 float4, coalesced
  f32x4* ezo = reinterpret_cast<f32x4*>(
      out + (size_t)NN * MM + ((size_t)m * NN + sbase) * KK);
#pragma unroll
  for (int it = 0; it < 4; ++it) ezo[it * 64 + l] = ezl4[it * 64 + l];

  // e_zz out: per iteration the wave writes one sample's full 16x16 tile
  // (64 lanes x float4 = 1KB, coalesced). lane l: row l>>2, col-quad l&3.
  const int i_ = l >> 2, jq = l & 3;
  const f32x4 mreg = reinterpret_cast<const f32x4*>(Mi)[l];  // per-lane
  f32x4* zzo = reinterpret_cast<f32x4*>(out + (size_t)NN * MM +
                                        (size_t)MM * NN * KK) +
               ((size_t)m * NN + sbase) * 64;
#pragma unroll 4
  for (int nl = 0; nl < 64; ++nl) {
    const float ezi = ez_l[((size_t)w * 64 + nl) * KK + i_];
    const f32x4 ezj = ezl4[nl * 4 + jq];
    zzo[nl * 64 + l] = mreg + ezi * ezj;
  }
}

// ---------------------------------------------------------------------------
// Kernel 3: softmax. 128 blocks x 64 threads. Reads scratch [M,N]
// (coalesced), writes resp [N,M] coalesced.
// ---------------------------------------------------------------------------
__global__ __launch_bounds__(64) void mfa_softmax(
    const float* __restrict__ scr, float* __restrict__ out) {
  const int n = blockIdx.x * 64 + threadIdx.x;
  float v[MM];
#pragma unroll
  for (int m = 0; m < MM; ++m) v[m] = scr[(size_t)m * NN + n];
  float mx = -3.4e38f;
#pragma unroll
  for (int i = 0; i < MM; ++i) mx = fmaxf(mx, v[i]);
  float s = 0.0f;
#pragma unroll
  for (int i = 0; i < MM; ++i) { v[i] = expf(v[i] - mx); s += v[i]; }
  const float inv = 1.0f / s;
  float4* p = reinterpret_cast<float4*>(out) + (size_t)n * (MM / 4);
#pragma unroll
  for (int i = 0; i < MM / 4; ++i) {
    float4 t;
    t.x = v[4 * i] * inv; t.y = v[4 * i + 1] * inv;
    t.z = v[4 * i + 2] * inv; t.w = v[4 * i + 3] * inv;
    p[i] = t;
  }
}

extern "C" void kernel_launch(void* const* d_in, const int* in_sizes, int n_in,
                              void* d_out, int out_size, void* d_ws,
                              size_t ws_size, hipStream_t stream) {
  const float* X = (const float*)d_in[0];
  const float* pi = (const float*)d_in[1];
  const float* mu = (const float*)d_in[2];
  const float* Lambda = (const float*)d_in[3];
  const float* Psi = (const float*)d_in[4];
  float* out = (float*)d_out;

  float* Minv = (float*)d_ws;            // 32*256 floats
  float* cconst = Minv + MM * KK * KK;   // 32
  float* scr = cconst + MM;              // 32*8192 floats = 1MB

  mfa_pre<<<MM, 64, 0, stream>>>(pi, Lambda, Psi, Minv, cconst);
  mfa_main<<<dim3(NN / 256, MM), 256, 0, stream>>>(X, mu, Lambda, Psi, Minv,
                                                   cconst, scr, out);
  mfa_softmax<<<NN / 64, 64, 0, stream>>>(scr, out);
}